// Round 4
// baseline (304.140 us; speedup 1.0000x reference)
//
#include <hip/hip_runtime.h>
#include <hip/hip_bf16.h>

#define D_MODEL 1024
#define S_LEN   2048
#define NBATCH  2
#define NHEADS  16
#define HDIM    64
#define DQKV    3072   // 3 * D_MODEL

typedef short bf16x8 __attribute__((ext_vector_type(8)));
typedef float f32x4  __attribute__((ext_vector_type(4)));
typedef float f32x16 __attribute__((ext_vector_type(16)));
typedef unsigned int u32;

// ---------------------------------------------------------------------------
// bf16 split helpers: x = hi + lo, each bf16 (RNE).
// ---------------------------------------------------------------------------
__device__ __forceinline__ unsigned short bf16_rne(float f) {
    unsigned u = __float_as_uint(f);
    return (unsigned short)((u + 0x7FFFu + ((u >> 16) & 1u)) >> 16);
}
__device__ __forceinline__ void bf16_split(float f, unsigned short& h, unsigned short& l) {
    h = bf16_rne(f);
    float hf = __uint_as_float(((unsigned)h) << 16);
    l = bf16_rne(f - hf);
}

__global__ __launch_bounds__(256) void split_f32_bf16(
    const float* __restrict__ in, unsigned short* __restrict__ hi,
    unsigned short* __restrict__ lo, int n4)
{
    int i = blockIdx.x * blockDim.x + threadIdx.x;
    const int stride = gridDim.x * blockDim.x;
    for (; i < n4; i += stride) {
        float4 v = ((const float4*)in)[i];
        float f[4] = {v.x, v.y, v.z, v.w};
        unsigned short hh[4], ll[4];
        #pragma unroll
        for (int j = 0; j < 4; ++j) bf16_split(f[j], hh[j], ll[j]);
        ((ushort4*)hi)[i] = make_ushort4(hh[0], hh[1], hh[2], hh[3]);
        ((ushort4*)lo)[i] = make_ushort4(ll[0], ll[1], ll[2], ll[3]);
    }
}

__device__ __forceinline__ void gld_lds16(const unsigned short* g, unsigned short* l) {
    __builtin_amdgcn_global_load_lds(
        (const __attribute__((address_space(1))) unsigned int*)g,
        (__attribute__((address_space(3))) unsigned int*)l, 16, 0, 0);
}

// Swizzled LDS fragment read: tile rows of 64 ushort (128B), byte ^= (row&7)<<4
__device__ __forceinline__ bf16x8 lds_frag(const unsigned short* base, int row, int e8) {
    int byte = (row << 7) + (e8 << 4);
    byte ^= (row & 7) << 4;
    return *(const bf16x8*)((const char*)base + byte);
}

// ---------------------------------------------------------------------------
// Generic split-bf16 MFMA GEMM (used for out-projection).
// C[M][N] = (Ah+Al)(Bh+Bl)^T + bias. 128x128 tile, BK=32, 4 waves.
// ---------------------------------------------------------------------------
__global__ __launch_bounds__(256) void gemm_mfma_split(
    const unsigned short* __restrict__ Ah, const unsigned short* __restrict__ Al,
    const unsigned short* __restrict__ Bh, const unsigned short* __restrict__ Bl,
    const float* __restrict__ bias, float* __restrict__ C,
    int M, int N, int K)
{
    __shared__ unsigned short sAh[128 * 32];
    __shared__ unsigned short sAl[128 * 32];
    __shared__ unsigned short sBh[128 * 32];
    __shared__ unsigned short sBl[128 * 32];

    const int tid  = threadIdx.x;
    const int lane = tid & 63;
    const int wid  = tid >> 6;
    const int bm = blockIdx.y * 128, bn = blockIdx.x * 128;
    const int wr = (wid >> 1) * 64, wc = (wid & 1) * 64;

    const unsigned short* gsrc = (wid == 0) ? Ah : (wid == 1) ? Al : (wid == 2) ? Bh : Bl;
    unsigned short* ldst = (wid == 0) ? sAh : (wid == 1) ? sAl : (wid == 2) ? sBh : sBl;
    const int brow = (wid < 2) ? bm : bn;
    const size_t rowbase = (size_t)(brow + (lane >> 2)) * K + (lane & 3) * 8;

    f32x4 acc[4][4];
    #pragma unroll
    for (int m = 0; m < 4; ++m)
        #pragma unroll
        for (int n = 0; n < 4; ++n)
            acc[m][n] = f32x4{0.f, 0.f, 0.f, 0.f};

    const int frA = (wr + (lane & 15)) * 32 + (lane >> 4) * 8;
    const int frB = (wc + (lane & 15)) * 32 + (lane >> 4) * 8;

    for (int k0 = 0; k0 < K; k0 += 32) {
        __syncthreads();
        const unsigned short* g = gsrc + rowbase + k0;
        #pragma unroll
        for (int c = 0; c < 8; ++c)
            gld_lds16(g + (size_t)c * 16 * K, ldst + c * 512);
        __syncthreads();

        bf16x8 ah[4], al[4], bh[4], bl[4];
        #pragma unroll
        for (int m = 0; m < 4; ++m) {
            ah[m] = *(const bf16x8*)&sAh[frA + m * 16 * 32];
            al[m] = *(const bf16x8*)&sAl[frA + m * 16 * 32];
        }
        #pragma unroll
        for (int n = 0; n < 4; ++n) {
            bh[n] = *(const bf16x8*)&sBh[frB + n * 16 * 32];
            bl[n] = *(const bf16x8*)&sBl[frB + n * 16 * 32];
        }
        #pragma unroll
        for (int m = 0; m < 4; ++m)
            #pragma unroll
            for (int n = 0; n < 4; ++n) {
                acc[m][n] = __builtin_amdgcn_mfma_f32_16x16x32_bf16(ah[m], bh[n], acc[m][n], 0, 0, 0);
                acc[m][n] = __builtin_amdgcn_mfma_f32_16x16x32_bf16(ah[m], bl[n], acc[m][n], 0, 0, 0);
                acc[m][n] = __builtin_amdgcn_mfma_f32_16x16x32_bf16(al[m], bh[n], acc[m][n], 0, 0, 0);
            }
    }

    #pragma unroll
    for (int n = 0; n < 4; ++n) {
        const int col = bn + wc + n * 16 + (lane & 15);
        const float bv = bias[col];
        #pragma unroll
        for (int m = 0; m < 4; ++m) {
            const int row0 = bm + wr + m * 16 + (lane >> 4) * 4;
            #pragma unroll
            for (int j = 0; j < 4; ++j)
                C[(size_t)(row0 + j) * N + col] = acc[m][n][j] + bv;
        }
    }
}

// ---------------------------------------------------------------------------
// QKV GEMM: same core, epilogue scatters into bf16 hi/lo planes:
//   Q plane [b,h,s,d] (pre-scaled by log2(e)/8), K plane [b,h,s,d],
//   Vt plane [b,h,d,s]
// ---------------------------------------------------------------------------
__global__ __launch_bounds__(256) void gemm_mfma_qkv(
    const unsigned short* __restrict__ Ah, const unsigned short* __restrict__ Al,
    const unsigned short* __restrict__ Bh, const unsigned short* __restrict__ Bl,
    const float* __restrict__ bias,
    unsigned short* __restrict__ Qh, unsigned short* __restrict__ Ql,
    unsigned short* __restrict__ Kh, unsigned short* __restrict__ Kl,
    unsigned short* __restrict__ Vth, unsigned short* __restrict__ Vtl,
    int M, int N, int K)
{
    __shared__ unsigned short sAh[128 * 32];
    __shared__ unsigned short sAl[128 * 32];
    __shared__ unsigned short sBh[128 * 32];
    __shared__ unsigned short sBl[128 * 32];

    const int tid  = threadIdx.x;
    const int lane = tid & 63;
    const int wid  = tid >> 6;
    const int bm = blockIdx.y * 128, bn = blockIdx.x * 128;
    const int wr = (wid >> 1) * 64, wc = (wid & 1) * 64;

    const unsigned short* gsrc = (wid == 0) ? Ah : (wid == 1) ? Al : (wid == 2) ? Bh : Bl;
    unsigned short* ldst = (wid == 0) ? sAh : (wid == 1) ? sAl : (wid == 2) ? sBh : sBl;
    const int brow = (wid < 2) ? bm : bn;
    const size_t rowbase = (size_t)(brow + (lane >> 2)) * K + (lane & 3) * 8;

    f32x4 acc[4][4];
    #pragma unroll
    for (int m = 0; m < 4; ++m)
        #pragma unroll
        for (int n = 0; n < 4; ++n)
            acc[m][n] = f32x4{0.f, 0.f, 0.f, 0.f};

    const int frA = (wr + (lane & 15)) * 32 + (lane >> 4) * 8;
    const int frB = (wc + (lane & 15)) * 32 + (lane >> 4) * 8;

    for (int k0 = 0; k0 < K; k0 += 32) {
        __syncthreads();
        const unsigned short* g = gsrc + rowbase + k0;
        #pragma unroll
        for (int c = 0; c < 8; ++c)
            gld_lds16(g + (size_t)c * 16 * K, ldst + c * 512);
        __syncthreads();

        bf16x8 ah[4], al[4], bh[4], bl[4];
        #pragma unroll
        for (int m = 0; m < 4; ++m) {
            ah[m] = *(const bf16x8*)&sAh[frA + m * 16 * 32];
            al[m] = *(const bf16x8*)&sAl[frA + m * 16 * 32];
        }
        #pragma unroll
        for (int n = 0; n < 4; ++n) {
            bh[n] = *(const bf16x8*)&sBh[frB + n * 16 * 32];
            bl[n] = *(const bf16x8*)&sBl[frB + n * 16 * 32];
        }
        #pragma unroll
        for (int m = 0; m < 4; ++m)
            #pragma unroll
            for (int n = 0; n < 4; ++n) {
                acc[m][n] = __builtin_amdgcn_mfma_f32_16x16x32_bf16(ah[m], bh[n], acc[m][n], 0, 0, 0);
                acc[m][n] = __builtin_amdgcn_mfma_f32_16x16x32_bf16(ah[m], bl[n], acc[m][n], 0, 0, 0);
                acc[m][n] = __builtin_amdgcn_mfma_f32_16x16x32_bf16(al[m], bh[n], acc[m][n], 0, 0, 0);
            }
    }

    #pragma unroll
    for (int n = 0; n < 4; ++n) {
        const int col = bn + wc + n * 16 + (lane & 15);
        const unsigned head = (unsigned)col / 192u;
        const int c = col - (int)head * 192;
        const int cls = c >> 6;                    // 0=q 1=k 2=v (uniform per n)
        const float bv = bias[col];
        #pragma unroll
        for (int m = 0; m < 4; ++m) {
            const int row0 = bm + wr + m * 16 + (lane >> 4) * 4;
            #pragma unroll
            for (int j = 0; j < 4; ++j) {
                const int row = row0 + j;
                const int bb = row >> 11, ss = row & 2047;
                float val = acc[m][n][j] + bv;
                // fold 1/sqrt(hd) * log2(e) into Q (softmax runs in exp2 domain)
                if (cls == 0) val *= 0.18033688011110918f;
                unsigned short vh_, vl_;
                bf16_split(val, vh_, vl_);
                if (cls == 2) {
                    const size_t idx = ((size_t)(bb * NHEADS + head) * HDIM + (c - 128)) * S_LEN + ss;
                    Vth[idx] = vh_; Vtl[idx] = vl_;
                } else {
                    const size_t idx = ((size_t)(bb * NHEADS + head) * S_LEN + ss) * HDIM + (c & 63);
                    if (cls == 0) { Qh[idx] = vh_; Ql[idx] = vl_; }
                    else          { Kh[idx] = vh_; Kl[idx] = vl_; }
                }
            }
        }
    }
}

// ---------------------------------------------------------------------------
// MFMA flash attention, double-buffered pipeline.
// Grid: 512 blocks (16 q-tiles x 32 bh), 4 waves. QBLK=128 (32 q/wave),
// KVBLK=64. Swapped QK^T (S^T = K.Q^T); softmax in exp2 domain; defer-max;
// tree reductions. Stage(t+1) issued before compute(t); one barrier/tile.
// ---------------------------------------------------------------------------
__global__ __launch_bounds__(256) void attn_mfma_kernel(
    const unsigned short* __restrict__ Qh, const unsigned short* __restrict__ Ql,
    const unsigned short* __restrict__ Kh, const unsigned short* __restrict__ Kl,
    const unsigned short* __restrict__ Vth, const unsigned short* __restrict__ Vtl,
    unsigned short* __restrict__ oh, unsigned short* __restrict__ ol)
{
    // [buf][plane hi/lo][64 rows x 64 cols]
    __shared__ unsigned short sK[2][2][64 * 64];
    __shared__ unsigned short sV[2][2][64 * 64];

    const int tid  = threadIdx.x;
    const int lane = tid & 63;
    const int wid  = tid >> 6;
    const int h    = lane >> 5;        // k-octet half
    const int qcol = lane & 31;

    // XCD-chunked remap: 512 blocks, XCD = bid%8 gets a contiguous 64-chunk
    const int bid = blockIdx.x;
    const int lb  = (bid & 7) * 64 + (bid >> 3);
    const int qt  = lb & 15;
    const int bh  = lb >> 4;

    const int q0 = qt * 128 + wid * 32;

    // ---- Q fragments in registers (pre-scaled at GEMM1) ----
    bf16x8 qfh[4], qfl[4];
    {
        const unsigned short* qrh = Qh + ((size_t)bh * S_LEN + q0 + qcol) * HDIM + h * 8;
        const unsigned short* qrl = Ql + ((size_t)bh * S_LEN + q0 + qcol) * HDIM + h * 8;
        #pragma unroll
        for (int ks = 0; ks < 4; ++ks) {
            qfh[ks] = *(const bf16x8*)(qrh + ks * 16);
            qfl[ks] = *(const bf16x8*)(qrl + ks * 16);
        }
    }

    // ---- staging setup: wave w stages plane w; inverse-swizzled source ----
    const unsigned short* gK = (wid == 0) ? Kh : Kl;
    const unsigned short* gV = (wid == 2) ? Vth : Vtl;
    const int r8   = lane >> 3;                      // row within 8-row chunk
    const int colb = ((lane & 7) ^ r8) << 3;         // inverse-swizzled col (elements)

    float m_run = -1e30f, l_run = 0.0f;
    f32x16 accO[2];
    #pragma unroll
    for (int m = 0; m < 2; ++m)
        #pragma unroll
        for (int r = 0; r < 16; ++r) accO[m][r] = 0.0f;

    // stage one 64x64 plane tile (8KB) for kv-tile at kt into buffer buf
    #define STAGE(buf, kt)                                                        \
        do {                                                                      \
            unsigned short* dst_ = (wid == 0) ? sK[buf][0] : (wid == 1) ? sK[buf][1] \
                                 : (wid == 2) ? sV[buf][0] : sV[buf][1];          \
            if (wid < 2) {                                                        \
                const unsigned short* g_ = gK + ((size_t)bh * S_LEN + (kt) + r8) * HDIM + colb; \
                _Pragma("unroll")                                                 \
                for (int c_ = 0; c_ < 8; ++c_)                                    \
                    gld_lds16(g_ + (size_t)c_ * 8 * HDIM, dst_ + c_ * 512);       \
            } else {                                                              \
                const unsigned short* g_ = gV + ((size_t)bh * HDIM + r8) * S_LEN + (kt) + colb; \
                _Pragma("unroll")                                                 \
                for (int c_ = 0; c_ < 8; ++c_)                                    \
                    gld_lds16(g_ + (size_t)c_ * 8 * S_LEN, dst_ + c_ * 512);      \
            }                                                                     \
        } while (0)

    STAGE(0, 0);
    __syncthreads();

    int cur = 0;
    for (int kt = 0; kt < S_LEN; kt += 64) {
        // ---- issue next tile's stage into the other buffer (overlaps compute)
        if (kt + 64 < S_LEN) STAGE(cur ^ 1, kt + 64);

        const unsigned short* cKh = sK[cur][0];
        const unsigned short* cKl = sK[cur][1];
        const unsigned short* cVh = sV[cur][0];
        const unsigned short* cVl = sV[cur][1];

        // ---- S^T = K . Q^T : accS[mm] is 32kv x 32q, lane owns q=qcol ----
        f32x16 accS[2];
        #pragma unroll
        for (int mm = 0; mm < 2; ++mm)
            #pragma unroll
            for (int r = 0; r < 16; ++r) accS[mm][r] = 0.0f;

        __builtin_amdgcn_s_setprio(1);
        #pragma unroll
        for (int ks = 0; ks < 4; ++ks) {
            const int e8 = ks * 2 + h;
            #pragma unroll
            for (int mm = 0; mm < 2; ++mm) {
                bf16x8 akh = lds_frag(cKh, mm * 32 + qcol, e8);
                bf16x8 akl = lds_frag(cKl, mm * 32 + qcol, e8);
                accS[mm] = __builtin_amdgcn_mfma_f32_32x32x16_bf16(akh, qfh[ks], accS[mm], 0, 0, 0);
                accS[mm] = __builtin_amdgcn_mfma_f32_32x32x16_bf16(akh, qfl[ks], accS[mm], 0, 0, 0);
                accS[mm] = __builtin_amdgcn_mfma_f32_32x32x16_bf16(akl, qfh[ks], accS[mm], 0, 0, 0);
            }
        }
        __builtin_amdgcn_s_setprio(0);

        // ---- online softmax (exp2 domain), tree reductions, defer-max ----
        float p[32];
        #pragma unroll
        for (int mm = 0; mm < 2; ++mm)
            #pragma unroll
            for (int r = 0; r < 16; ++r) p[mm * 16 + r] = accS[mm][r];

        float t16[16];
        #pragma unroll
        for (int i = 0; i < 16; ++i) t16[i] = fmaxf(p[i], p[i + 16]);
        float t8[8];
        #pragma unroll
        for (int i = 0; i < 8; ++i) t8[i] = fmaxf(t16[i], t16[i + 8]);
        float t4[4];
        #pragma unroll
        for (int i = 0; i < 4; ++i) t4[i] = fmaxf(t8[i], t8[i + 4]);
        float mx = fmaxf(fmaxf(t4[0], t4[1]), fmaxf(t4[2], t4[3]));
        mx = fmaxf(mx, __shfl_xor(mx, 32));

        if (!__all(mx <= m_run + 8.0f)) {
            const float mnew = fmaxf(m_run, mx);
            const float corr = exp2f(m_run - mnew);
            m_run = mnew;
            l_run *= corr;
            #pragma unroll
            for (int m = 0; m < 2; ++m)
                #pragma unroll
                for (int r = 0; r < 16; ++r) accO[m][r] *= corr;
        }

        #pragma unroll
        for (int i = 0; i < 32; ++i) p[i] = exp2f(p[i] - m_run);
        float s16[16];
        #pragma unroll
        for (int i = 0; i < 16; ++i) s16[i] = p[i] + p[i + 16];
        float s8[8];
        #pragma unroll
        for (int i = 0; i < 8; ++i) s8[i] = s16[i] + s16[i + 8];
        float s4[4];
        #pragma unroll
        for (int i = 0; i < 4; ++i) s4[i] = s8[i] + s8[i + 4];
        float rs = (s4[0] + s4[1]) + (s4[2] + s4[3]);
        rs += __shfl_xor(rs, 32);
        l_run += rs;

        // ---- P^T -> bf16 hi/lo B-fragments (cvt_pk + shfl_xor(32)) + PV ----
        const bool hib = (h != 0);
        #pragma unroll
        for (int mm = 0; mm < 2; ++mm) {
            u32 wh_[8], wl_[8], sh_[8], sl_[8];
            #pragma unroll
            for (int i = 0; i < 8; ++i) {
                const float pe = p[mm * 16 + 2 * i], po = p[mm * 16 + 2 * i + 1];
                u32 a_;
                asm("v_cvt_pk_bf16_f32 %0, %1, %2" : "=v"(a_) : "v"(pe), "v"(po));
                const float he = __uint_as_float(a_ << 16);
                const float ho = __uint_as_float(a_ & 0xffff0000u);
                u32 b_;
                asm("v_cvt_pk_bf16_f32 %0, %1, %2" : "=v"(b_) : "v"(pe - he), "v"(po - ho));
                wh_[i] = a_; wl_[i] = b_;
            }
            #pragma unroll
            for (int i = 0; i < 8; ++i) {
                sh_[i] = __shfl_xor(wh_[i], 32);
                sl_[i] = __shfl_xor(wl_[i], 32);
            }
            #pragma unroll
            for (int cc = 0; cc < 2; ++cc) {
                const int b0 = cc * 4;
                union { u32 w[4]; bf16x8 v; } uh, ul;
                uh.w[0] = hib ? sh_[b0 + 2] : wh_[b0 + 0];
                uh.w[1] = hib ? sh_[b0 + 3] : wh_[b0 + 1];
                uh.w[2] = hib ? wh_[b0 + 2] : sh_[b0 + 0];
                uh.w[3] = hib ? wh_[b0 + 3] : sh_[b0 + 1];
                ul.w[0] = hib ? sl_[b0 + 2] : wl_[b0 + 0];
                ul.w[1] = hib ? sl_[b0 + 3] : wl_[b0 + 1];
                ul.w[2] = hib ? wl_[b0 + 2] : sl_[b0 + 0];
                ul.w[3] = hib ? wl_[b0 + 3] : sl_[b0 + 1];
                const int e8 = (mm * 2 + cc) * 2 + h;   // kv octet
                __builtin_amdgcn_s_setprio(1);
                #pragma unroll
                for (int mdc = 0; mdc < 2; ++mdc) {
                    bf16x8 vhf = lds_frag(cVh, mdc * 32 + qcol, e8);
                    bf16x8 vlf = lds_frag(cVl, mdc * 32 + qcol, e8);
                    accO[mdc] = __builtin_amdgcn_mfma_f32_32x32x16_bf16(vhf, uh.v, accO[mdc], 0, 0, 0);
                    accO[mdc] = __builtin_amdgcn_mfma_f32_32x32x16_bf16(vhf, ul.v, accO[mdc], 0, 0, 0);
                    accO[mdc] = __builtin_amdgcn_mfma_f32_32x32x16_bf16(vlf, uh.v, accO[mdc], 0, 0, 0);
                }
                __builtin_amdgcn_s_setprio(0);
            }
        }

        // waits my stage loads (vmcnt) + everyone (barrier); next buf ready
        __syncthreads();
        cur ^= 1;
    }
    #undef STAGE

    // ---- epilogue: O^T[d][q] -> bf16 hi/lo planes [token][h*64+d] ----
    const float inv = 1.0f / l_run;
    const int bb = bh >> 4, hh = bh & 15;
    const int ss = q0 + qcol;
    unsigned short* po_h = oh + ((size_t)(bb * S_LEN + ss)) * D_MODEL + hh * HDIM;
    unsigned short* po_l = ol + ((size_t)(bb * S_LEN + ss)) * D_MODEL + hh * HDIM;
    #pragma unroll
    for (int mdc = 0; mdc < 2; ++mdc)
        #pragma unroll
        for (int r = 0; r < 16; r += 2) {
            const int d = mdc * 32 + (r & 3) + 8 * (r >> 2) + 4 * h;
            const float v0 = accO[mdc][r] * inv, v1 = accO[mdc][r + 1] * inv;
            unsigned short h0, l0, h1, l1;
            bf16_split(v0, h0, l0);
            bf16_split(v1, h1, l1);
            *(u32*)(po_h + d) = ((u32)h1 << 16) | h0;
            *(u32*)(po_l + d) = ((u32)l1 << 16) | l0;
        }
}

// ---------------------------------------------------------------------------
extern "C" void kernel_launch(void* const* d_in, const int* in_sizes, int n_in,
                              void* d_out, int out_size, void* d_ws, size_t ws_size,
                              hipStream_t stream)
{
    const float* x     = (const float*)d_in[0];
    const float* w_qkv = (const float*)d_in[1];
    const float* b_qkv = (const float*)d_in[2];
    const float* w_out = (const float*)d_in[3];
    const float* b_out = (const float*)d_in[4];
    float* out = (float*)d_out;

    const int M = NBATCH * S_LEN;  // 4096
    const size_t PL = (size_t)32 * S_LEN * HDIM;   // 4,194,304 elems = 8 MB

    // ws layout (64 MB of >= 67.1 MB):
    //  [0..8M)   Qh   [8..16) Ql   [16..24) Kh   [24..32) Kl
    //  [32..40)  Vth  [40..48) Vtl [48..56)  xh  [56..64)  xl
    unsigned short* Qh  = (unsigned short*)d_ws;
    unsigned short* Ql  = Qh  + PL;
    unsigned short* Kh  = Ql  + PL;
    unsigned short* Kl  = Kh  + PL;
    unsigned short* Vth = Kl  + PL;
    unsigned short* Vtl = Vth + PL;
    unsigned short* xh  = Vtl + PL;
    unsigned short* xl  = xh  + PL;
    // aliases (stream-ordered reuse):
    unsigned short* wqh = (unsigned short*)d_out;          // dead before gemm2 writes
    unsigned short* wql = wqh + (size_t)DQKV * D_MODEL;
    unsigned short* aoh = xh;                              // x dead after gemm1
    unsigned short* aol = xl;
    unsigned short* woh = Qh;                              // Q planes dead after attn
    unsigned short* wol = Qh + (size_t)D_MODEL * D_MODEL;

    dim3 blk(256);
    split_f32_bf16<<<1024, blk, 0, stream>>>(x, xh, xl, M * D_MODEL / 4);
    split_f32_bf16<<<1024, blk, 0, stream>>>(w_qkv, wqh, wql, DQKV * D_MODEL / 4);

    gemm_mfma_qkv<<<dim3(DQKV / 128, M / 128), blk, 0, stream>>>(
        xh, xl, wqh, wql, b_qkv, Qh, Ql, Kh, Kl, Vth, Vtl, M, DQKV, D_MODEL);

    attn_mfma_kernel<<<dim3(512), blk, 0, stream>>>(Qh, Ql, Kh, Kl, Vth, Vtl, aoh, aol);

    split_f32_bf16<<<512, blk, 0, stream>>>(w_out, woh, wol, D_MODEL * D_MODEL / 4);

    gemm_mfma_split<<<dim3(D_MODEL / 128, M / 128), blk, 0, stream>>>(
        aoh, aol, woh, wol, b_out, out, M, D_MODEL, D_MODEL);
}

// Round 5
// 293.546 us; speedup vs baseline: 1.0361x; 1.0361x over previous
//
#include <hip/hip_runtime.h>
#include <hip/hip_bf16.h>

#define D_MODEL 1024
#define S_LEN   2048
#define NBATCH  2
#define NHEADS  16
#define HDIM    64
#define DQKV    3072   // 3 * D_MODEL

typedef short bf16x8 __attribute__((ext_vector_type(8)));
typedef float f32x4  __attribute__((ext_vector_type(4)));
typedef float f32x16 __attribute__((ext_vector_type(16)));
typedef unsigned int u32;

// ---------------------------------------------------------------------------
// bf16 split helpers: x = hi + lo, each bf16 (RNE).
// ---------------------------------------------------------------------------
__device__ __forceinline__ unsigned short bf16_rne(float f) {
    unsigned u = __float_as_uint(f);
    return (unsigned short)((u + 0x7FFFu + ((u >> 16) & 1u)) >> 16);
}
__device__ __forceinline__ void bf16_split(float f, unsigned short& h, unsigned short& l) {
    h = bf16_rne(f);
    float hf = __uint_as_float(((unsigned)h) << 16);
    l = bf16_rne(f - hf);
}

__global__ __launch_bounds__(256) void split_f32_bf16(
    const float* __restrict__ in, unsigned short* __restrict__ hi,
    unsigned short* __restrict__ lo, int n4)
{
    int i = blockIdx.x * blockDim.x + threadIdx.x;
    const int stride = gridDim.x * blockDim.x;
    for (; i < n4; i += stride) {
        float4 v = ((const float4*)in)[i];
        float f[4] = {v.x, v.y, v.z, v.w};
        unsigned short hh[4], ll[4];
        #pragma unroll
        for (int j = 0; j < 4; ++j) bf16_split(f[j], hh[j], ll[j]);
        ((ushort4*)hi)[i] = make_ushort4(hh[0], hh[1], hh[2], hh[3]);
        ((ushort4*)lo)[i] = make_ushort4(ll[0], ll[1], ll[2], ll[3]);
    }
}

__device__ __forceinline__ void gld_lds16(const unsigned short* g, unsigned short* l) {
    __builtin_amdgcn_global_load_lds(
        (const __attribute__((address_space(1))) unsigned int*)g,
        (__attribute__((address_space(3))) unsigned int*)l, 16, 0, 0);
}

// Swizzled LDS fragment read: tile rows of 64 ushort (128B), byte ^= (row&7)<<4
__device__ __forceinline__ bf16x8 lds_frag(const unsigned short* base, int row, int e8) {
    int byte = (row << 7) + (e8 << 4);
    byte ^= (row & 7) << 4;
    return *(const bf16x8*)((const char*)base + byte);
}

// ---------------------------------------------------------------------------
// Generic split-bf16 MFMA GEMM (used for out-projection).
// C[M][N] = (Ah+Al)(Bh+Bl)^T + bias. 128x128 tile, BK=32, 4 waves.
// ---------------------------------------------------------------------------
__global__ __launch_bounds__(256) void gemm_mfma_split(
    const unsigned short* __restrict__ Ah, const unsigned short* __restrict__ Al,
    const unsigned short* __restrict__ Bh, const unsigned short* __restrict__ Bl,
    const float* __restrict__ bias, float* __restrict__ C,
    int M, int N, int K)
{
    __shared__ unsigned short sAh[128 * 32];
    __shared__ unsigned short sAl[128 * 32];
    __shared__ unsigned short sBh[128 * 32];
    __shared__ unsigned short sBl[128 * 32];

    const int tid  = threadIdx.x;
    const int lane = tid & 63;
    const int wid  = tid >> 6;
    const int bm = blockIdx.y * 128, bn = blockIdx.x * 128;
    const int wr = (wid >> 1) * 64, wc = (wid & 1) * 64;

    const unsigned short* gsrc = (wid == 0) ? Ah : (wid == 1) ? Al : (wid == 2) ? Bh : Bl;
    unsigned short* ldst = (wid == 0) ? sAh : (wid == 1) ? sAl : (wid == 2) ? sBh : sBl;
    const int brow = (wid < 2) ? bm : bn;
    const size_t rowbase = (size_t)(brow + (lane >> 2)) * K + (lane & 3) * 8;

    f32x4 acc[4][4];
    #pragma unroll
    for (int m = 0; m < 4; ++m)
        #pragma unroll
        for (int n = 0; n < 4; ++n)
            acc[m][n] = f32x4{0.f, 0.f, 0.f, 0.f};

    const int frA = (wr + (lane & 15)) * 32 + (lane >> 4) * 8;
    const int frB = (wc + (lane & 15)) * 32 + (lane >> 4) * 8;

    for (int k0 = 0; k0 < K; k0 += 32) {
        __syncthreads();
        const unsigned short* g = gsrc + rowbase + k0;
        #pragma unroll
        for (int c = 0; c < 8; ++c)
            gld_lds16(g + (size_t)c * 16 * K, ldst + c * 512);
        __syncthreads();

        bf16x8 ah[4], al[4], bh[4], bl[4];
        #pragma unroll
        for (int m = 0; m < 4; ++m) {
            ah[m] = *(const bf16x8*)&sAh[frA + m * 16 * 32];
            al[m] = *(const bf16x8*)&sAl[frA + m * 16 * 32];
        }
        #pragma unroll
        for (int n = 0; n < 4; ++n) {
            bh[n] = *(const bf16x8*)&sBh[frB + n * 16 * 32];
            bl[n] = *(const bf16x8*)&sBl[frB + n * 16 * 32];
        }
        #pragma unroll
        for (int m = 0; m < 4; ++m)
            #pragma unroll
            for (int n = 0; n < 4; ++n) {
                acc[m][n] = __builtin_amdgcn_mfma_f32_16x16x32_bf16(ah[m], bh[n], acc[m][n], 0, 0, 0);
                acc[m][n] = __builtin_amdgcn_mfma_f32_16x16x32_bf16(ah[m], bl[n], acc[m][n], 0, 0, 0);
                acc[m][n] = __builtin_amdgcn_mfma_f32_16x16x32_bf16(al[m], bh[n], acc[m][n], 0, 0, 0);
            }
    }

    #pragma unroll
    for (int n = 0; n < 4; ++n) {
        const int col = bn + wc + n * 16 + (lane & 15);
        const float bv = bias[col];
        #pragma unroll
        for (int m = 0; m < 4; ++m) {
            const int row0 = bm + wr + m * 16 + (lane >> 4) * 4;
            #pragma unroll
            for (int j = 0; j < 4; ++j)
                C[(size_t)(row0 + j) * N + col] = acc[m][n][j] + bv;
        }
    }
}

// ---------------------------------------------------------------------------
// QKV GEMM: same core, epilogue scatters into bf16 hi/lo planes:
//   Q plane [b,h,s,d] (pre-scaled by log2(e)/8), K plane [b,h,s,d],
//   Vt plane [b,h,d,s]
// ---------------------------------------------------------------------------
__global__ __launch_bounds__(256) void gemm_mfma_qkv(
    const unsigned short* __restrict__ Ah, const unsigned short* __restrict__ Al,
    const unsigned short* __restrict__ Bh, const unsigned short* __restrict__ Bl,
    const float* __restrict__ bias,
    unsigned short* __restrict__ Qh, unsigned short* __restrict__ Ql,
    unsigned short* __restrict__ Kh, unsigned short* __restrict__ Kl,
    unsigned short* __restrict__ Vth, unsigned short* __restrict__ Vtl,
    int M, int N, int K)
{
    __shared__ unsigned short sAh[128 * 32];
    __shared__ unsigned short sAl[128 * 32];
    __shared__ unsigned short sBh[128 * 32];
    __shared__ unsigned short sBl[128 * 32];

    const int tid  = threadIdx.x;
    const int lane = tid & 63;
    const int wid  = tid >> 6;
    const int bm = blockIdx.y * 128, bn = blockIdx.x * 128;
    const int wr = (wid >> 1) * 64, wc = (wid & 1) * 64;

    const unsigned short* gsrc = (wid == 0) ? Ah : (wid == 1) ? Al : (wid == 2) ? Bh : Bl;
    unsigned short* ldst = (wid == 0) ? sAh : (wid == 1) ? sAl : (wid == 2) ? sBh : sBl;
    const int brow = (wid < 2) ? bm : bn;
    const size_t rowbase = (size_t)(brow + (lane >> 2)) * K + (lane & 3) * 8;

    f32x4 acc[4][4];
    #pragma unroll
    for (int m = 0; m < 4; ++m)
        #pragma unroll
        for (int n = 0; n < 4; ++n)
            acc[m][n] = f32x4{0.f, 0.f, 0.f, 0.f};

    const int frA = (wr + (lane & 15)) * 32 + (lane >> 4) * 8;
    const int frB = (wc + (lane & 15)) * 32 + (lane >> 4) * 8;

    for (int k0 = 0; k0 < K; k0 += 32) {
        __syncthreads();
        const unsigned short* g = gsrc + rowbase + k0;
        #pragma unroll
        for (int c = 0; c < 8; ++c)
            gld_lds16(g + (size_t)c * 16 * K, ldst + c * 512);
        __syncthreads();

        bf16x8 ah[4], al[4], bh[4], bl[4];
        #pragma unroll
        for (int m = 0; m < 4; ++m) {
            ah[m] = *(const bf16x8*)&sAh[frA + m * 16 * 32];
            al[m] = *(const bf16x8*)&sAl[frA + m * 16 * 32];
        }
        #pragma unroll
        for (int n = 0; n < 4; ++n) {
            bh[n] = *(const bf16x8*)&sBh[frB + n * 16 * 32];
            bl[n] = *(const bf16x8*)&sBl[frB + n * 16 * 32];
        }
        #pragma unroll
        for (int m = 0; m < 4; ++m)
            #pragma unroll
            for (int n = 0; n < 4; ++n) {
                acc[m][n] = __builtin_amdgcn_mfma_f32_16x16x32_bf16(ah[m], bh[n], acc[m][n], 0, 0, 0);
                acc[m][n] = __builtin_amdgcn_mfma_f32_16x16x32_bf16(ah[m], bl[n], acc[m][n], 0, 0, 0);
                acc[m][n] = __builtin_amdgcn_mfma_f32_16x16x32_bf16(al[m], bh[n], acc[m][n], 0, 0, 0);
            }
    }

    #pragma unroll
    for (int n = 0; n < 4; ++n) {
        const int col = bn + wc + n * 16 + (lane & 15);
        const unsigned head = (unsigned)col / 192u;
        const int c = col - (int)head * 192;
        const int cls = c >> 6;                    // 0=q 1=k 2=v (uniform per n)
        const float bv = bias[col];
        #pragma unroll
        for (int m = 0; m < 4; ++m) {
            const int row0 = bm + wr + m * 16 + (lane >> 4) * 4;
            #pragma unroll
            for (int j = 0; j < 4; ++j) {
                const int row = row0 + j;
                const int bb = row >> 11, ss = row & 2047;
                float val = acc[m][n][j] + bv;
                // fold 1/sqrt(hd) * log2(e) into Q (softmax runs in exp2 domain)
                if (cls == 0) val *= 0.18033688011110918f;
                unsigned short vh_, vl_;
                bf16_split(val, vh_, vl_);
                if (cls == 2) {
                    const size_t idx = ((size_t)(bb * NHEADS + head) * HDIM + (c - 128)) * S_LEN + ss;
                    Vth[idx] = vh_; Vtl[idx] = vl_;
                } else {
                    const size_t idx = ((size_t)(bb * NHEADS + head) * S_LEN + ss) * HDIM + (c & 63);
                    if (cls == 0) { Qh[idx] = vh_; Ql[idx] = vl_; }
                    else          { Kh[idx] = vh_; Kl[idx] = vl_; }
                }
            }
        }
    }
}

// ---------------------------------------------------------------------------
// MFMA flash attention, kv-split. Grid: 512 blocks x 8 waves (512 thr).
// Waves 0-3 process even 64-kv-tiles, waves 4-7 odd tiles; wave w and w+4
// share the same 32 q-columns and merge (m,l,O) at the end via LDS.
// 4096 waves total -> 16 waves/CU -> 4/SIMD (vs 2/SIMD before).
// Single-buffered LDS: 8 planes x 8KB = 64KB; wave w stages plane w.
// Softmax in exp2 domain (Q pre-scaled by log2e/8), raw v_exp_f32.
// ---------------------------------------------------------------------------
__global__ __launch_bounds__(512) void attn_mfma_kernel(
    const unsigned short* __restrict__ Qh, const unsigned short* __restrict__ Ql,
    const unsigned short* __restrict__ Kh, const unsigned short* __restrict__ Kl,
    const unsigned short* __restrict__ Vth, const unsigned short* __restrict__ Vtl,
    unsigned short* __restrict__ oh, unsigned short* __restrict__ ol)
{
    // planes: [par*4 + {0:Kh,1:Kl,2:Vh,3:Vl}], each 64x64 bf16 = 8KB
    __shared__ unsigned short smem[8][4096];

    const int tid  = threadIdx.x;
    const int lane = tid & 63;
    const int wid  = tid >> 6;         // 0..7
    const int wq   = wid & 3;          // q sub-tile (32 cols)
    const int par  = wid >> 2;         // kv parity (0=even tiles, 1=odd)
    const int h    = lane >> 5;        // k-octet half
    const int qcol = lane & 31;

    // XCD-chunked remap: 512 blocks, XCD = bid%8 gets a contiguous 64-chunk
    const int bid = blockIdx.x;
    const int lb  = (bid & 7) * 64 + (bid >> 3);
    const int qt  = lb & 15;
    const int bh  = lb >> 4;
    const int q0  = qt * 128 + wq * 32;

    // ---- Q fragments in registers (pre-scaled at GEMM1) ----
    bf16x8 qfh[4], qfl[4];
    {
        const unsigned short* qrh = Qh + ((size_t)bh * S_LEN + q0 + qcol) * HDIM + h * 8;
        const unsigned short* qrl = Ql + ((size_t)bh * S_LEN + q0 + qcol) * HDIM + h * 8;
        #pragma unroll
        for (int ks = 0; ks < 4; ++ks) {
            qfh[ks] = *(const bf16x8*)(qrh + ks * 16);
            qfl[ks] = *(const bf16x8*)(qrl + ks * 16);
        }
    }

    // ---- staging: wave w stages plane w (class=wq, parity=par) ----
    const unsigned short* gKV = (wq == 0) ? Kh : (wq == 1) ? Kl : (wq == 2) ? Vth : Vtl;
    unsigned short* myplane = smem[wid];
    const int r8   = lane >> 3;                      // row within 8-row chunk
    const int colb = ((lane & 7) ^ r8) << 3;         // inverse-swizzled col (elements)

    // ---- compute planes for this wave's parity ----
    const unsigned short* cKh = smem[par * 4 + 0];
    const unsigned short* cKl = smem[par * 4 + 1];
    const unsigned short* cVh = smem[par * 4 + 2];
    const unsigned short* cVl = smem[par * 4 + 3];

    float m_run = -1e30f, l_run = 0.0f;
    f32x16 accO[2];
    #pragma unroll
    for (int m = 0; m < 2; ++m)
        #pragma unroll
        for (int r = 0; r < 16; ++r) accO[m][r] = 0.0f;

    for (int it = 0; it < S_LEN / 128; ++it) {       // 16 iterations
        const int kt = it * 128 + par * 64;          // this parity's kv tile
        __syncthreads();   // previous tile's LDS reads done (all waves)
        if (wq < 2) {      // K plane: rows [64][HDIM]
            const unsigned short* g_ = gKV + ((size_t)bh * S_LEN + kt + r8) * HDIM + colb;
            #pragma unroll
            for (int c = 0; c < 8; ++c)
                gld_lds16(g_ + (size_t)c * 8 * HDIM, myplane + c * 512);
        } else {           // V^T plane: rows [HDIM][S_LEN]
            const unsigned short* g_ = gKV + ((size_t)bh * HDIM + r8) * S_LEN + kt + colb;
            #pragma unroll
            for (int c = 0; c < 8; ++c)
                gld_lds16(g_ + (size_t)c * 8 * S_LEN, myplane + c * 512);
        }
        __syncthreads();   // staging complete (vmcnt drained at barrier)

        // ---- S^T = K . Q^T : accS[mm] is 32kv x 32q, lane owns q=qcol ----
        f32x16 accS[2];
        #pragma unroll
        for (int mm = 0; mm < 2; ++mm)
            #pragma unroll
            for (int r = 0; r < 16; ++r) accS[mm][r] = 0.0f;

        __builtin_amdgcn_s_setprio(1);
        #pragma unroll
        for (int ks = 0; ks < 4; ++ks) {
            const int e8 = ks * 2 + h;
            #pragma unroll
            for (int mm = 0; mm < 2; ++mm) {
                bf16x8 akh = lds_frag(cKh, mm * 32 + qcol, e8);
                bf16x8 akl = lds_frag(cKl, mm * 32 + qcol, e8);
                accS[mm] = __builtin_amdgcn_mfma_f32_32x32x16_bf16(akh, qfh[ks], accS[mm], 0, 0, 0);
                accS[mm] = __builtin_amdgcn_mfma_f32_32x32x16_bf16(akh, qfl[ks], accS[mm], 0, 0, 0);
                accS[mm] = __builtin_amdgcn_mfma_f32_32x32x16_bf16(akl, qfh[ks], accS[mm], 0, 0, 0);
            }
        }
        __builtin_amdgcn_s_setprio(0);

        // ---- online softmax (exp2 domain), tree reductions, defer-max ----
        float p[32];
        #pragma unroll
        for (int mm = 0; mm < 2; ++mm)
            #pragma unroll
            for (int r = 0; r < 16; ++r) p[mm * 16 + r] = accS[mm][r];

        float t16[16];
        #pragma unroll
        for (int i = 0; i < 16; ++i) t16[i] = fmaxf(p[i], p[i + 16]);
        float t8[8];
        #pragma unroll
        for (int i = 0; i < 8; ++i) t8[i] = fmaxf(t16[i], t16[i + 8]);
        float t4[4];
        #pragma unroll
        for (int i = 0; i < 4; ++i) t4[i] = fmaxf(t8[i], t8[i + 4]);
        float mx = fmaxf(fmaxf(t4[0], t4[1]), fmaxf(t4[2], t4[3]));
        mx = fmaxf(mx, __shfl_xor(mx, 32));

        if (!__all(mx <= m_run + 8.0f)) {
            const float mnew = fmaxf(m_run, mx);
            const float corr = __builtin_amdgcn_exp2f(m_run - mnew);
            m_run = mnew;
            l_run *= corr;
            #pragma unroll
            for (int m = 0; m < 2; ++m)
                #pragma unroll
                for (int r = 0; r < 16; ++r) accO[m][r] *= corr;
        }

        #pragma unroll
        for (int i = 0; i < 32; ++i) p[i] = __builtin_amdgcn_exp2f(p[i] - m_run);
        float s16[16];
        #pragma unroll
        for (int i = 0; i < 16; ++i) s16[i] = p[i] + p[i + 16];
        float s8[8];
        #pragma unroll
        for (int i = 0; i < 8; ++i) s8[i] = s16[i] + s16[i + 8];
        float s4[4];
        #pragma unroll
        for (int i = 0; i < 4; ++i) s4[i] = s8[i] + s8[i + 4];
        float rs = (s4[0] + s4[1]) + (s4[2] + s4[3]);
        rs += __shfl_xor(rs, 32);
        l_run += rs;

        // ---- P^T -> bf16 hi/lo B-fragments (cvt_pk + shfl_xor(32)) + PV ----
        const bool hib = (h != 0);
        #pragma unroll
        for (int mm = 0; mm < 2; ++mm) {
            u32 wh_[8], wl_[8], sh_[8], sl_[8];
            #pragma unroll
            for (int i = 0; i < 8; ++i) {
                const float pe = p[mm * 16 + 2 * i], po = p[mm * 16 + 2 * i + 1];
                u32 a_;
                asm("v_cvt_pk_bf16_f32 %0, %1, %2" : "=v"(a_) : "v"(pe), "v"(po));
                const float he = __uint_as_float(a_ << 16);
                const float ho = __uint_as_float(a_ & 0xffff0000u);
                u32 b_;
                asm("v_cvt_pk_bf16_f32 %0, %1, %2" : "=v"(b_) : "v"(pe - he), "v"(po - ho));
                wh_[i] = a_; wl_[i] = b_;
            }
            #pragma unroll
            for (int i = 0; i < 8; ++i) {
                sh_[i] = __shfl_xor(wh_[i], 32);
                sl_[i] = __shfl_xor(wl_[i], 32);
            }
            #pragma unroll
            for (int cc = 0; cc < 2; ++cc) {
                const int b0 = cc * 4;
                union { u32 w[4]; bf16x8 v; } uh, ul;
                uh.w[0] = hib ? sh_[b0 + 2] : wh_[b0 + 0];
                uh.w[1] = hib ? sh_[b0 + 3] : wh_[b0 + 1];
                uh.w[2] = hib ? wh_[b0 + 2] : sh_[b0 + 0];
                uh.w[3] = hib ? wh_[b0 + 3] : sh_[b0 + 1];
                ul.w[0] = hib ? sl_[b0 + 2] : wl_[b0 + 0];
                ul.w[1] = hib ? sl_[b0 + 3] : wl_[b0 + 1];
                ul.w[2] = hib ? wl_[b0 + 2] : sl_[b0 + 0];
                ul.w[3] = hib ? wl_[b0 + 3] : sl_[b0 + 1];
                const int e8 = (mm * 2 + cc) * 2 + h;   // kv octet
                #pragma unroll
                for (int mdc = 0; mdc < 2; ++mdc) {
                    bf16x8 vhf = lds_frag(cVh, mdc * 32 + qcol, e8);
                    bf16x8 vlf = lds_frag(cVl, mdc * 32 + qcol, e8);
                    accO[mdc] = __builtin_amdgcn_mfma_f32_32x32x16_bf16(vhf, uh.v, accO[mdc], 0, 0, 0);
                    accO[mdc] = __builtin_amdgcn_mfma_f32_32x32x16_bf16(vhf, ul.v, accO[mdc], 0, 0, 0);
                    accO[mdc] = __builtin_amdgcn_mfma_f32_32x32x16_bf16(vlf, uh.v, accO[mdc], 0, 0, 0);
                }
            }
        }
    }

    // ---- merge parity pair states via LDS, then epilogue (par 0 writes) ----
    __syncthreads();               // all compute done; LDS reusable
    float* mbuf = (float*)&smem[0][0];   // 64KB float view; need 35KB
    if (par == 1) {
        float* dst = mbuf + ((size_t)(wq * 64 + lane)) * 35;  // stride 35: conflict-free
        #pragma unroll
        for (int mdc = 0; mdc < 2; ++mdc)
            #pragma unroll
            for (int r = 0; r < 16; ++r) dst[mdc * 16 + r] = accO[mdc][r];
        dst[32] = m_run;
        dst[33] = l_run;
    }
    __syncthreads();
    if (par == 0) {
        const float* src = mbuf + ((size_t)(wq * 64 + lane)) * 35;
        const float m2 = src[32], l2 = src[33];
        const float mt = fmaxf(m_run, m2);
        const float w1 = __builtin_amdgcn_exp2f(m_run - mt);
        const float w2 = __builtin_amdgcn_exp2f(m2 - mt);
        const float inv = 1.0f / (l_run * w1 + l2 * w2);

        const int bb = bh >> 4, hh = bh & 15;
        const int ss = q0 + qcol;
        unsigned short* po_h = oh + ((size_t)(bb * S_LEN + ss)) * D_MODEL + hh * HDIM;
        unsigned short* po_l = ol + ((size_t)(bb * S_LEN + ss)) * D_MODEL + hh * HDIM;
        #pragma unroll
        for (int mdc = 0; mdc < 2; ++mdc)
            #pragma unroll
            for (int r = 0; r < 16; r += 2) {
                const int d = mdc * 32 + (r & 3) + 8 * (r >> 2) + 4 * h;
                const float v0 = (accO[mdc][r]     * w1 + src[mdc * 16 + r]     * w2) * inv;
                const float v1 = (accO[mdc][r + 1] * w1 + src[mdc * 16 + r + 1] * w2) * inv;
                unsigned short h0, l0, h1, l1;
                bf16_split(v0, h0, l0);
                bf16_split(v1, h1, l1);
                *(u32*)(po_h + d) = ((u32)h1 << 16) | h0;
                *(u32*)(po_l + d) = ((u32)l1 << 16) | l0;
            }
    }
}

// ---------------------------------------------------------------------------
extern "C" void kernel_launch(void* const* d_in, const int* in_sizes, int n_in,
                              void* d_out, int out_size, void* d_ws, size_t ws_size,
                              hipStream_t stream)
{
    const float* x     = (const float*)d_in[0];
    const float* w_qkv = (const float*)d_in[1];
    const float* b_qkv = (const float*)d_in[2];
    const float* w_out = (const float*)d_in[3];
    const float* b_out = (const float*)d_in[4];
    float* out = (float*)d_out;

    const int M = NBATCH * S_LEN;  // 4096
    const size_t PL = (size_t)32 * S_LEN * HDIM;   // 4,194,304 elems = 8 MB

    // ws layout (64 MB of >= 67.1 MB):
    //  [0..8M)   Qh   [8..16) Ql   [16..24) Kh   [24..32) Kl
    //  [32..40)  Vth  [40..48) Vtl [48..56)  xh  [56..64)  xl
    unsigned short* Qh  = (unsigned short*)d_ws;
    unsigned short* Ql  = Qh  + PL;
    unsigned short* Kh  = Ql  + PL;
    unsigned short* Kl  = Kh  + PL;
    unsigned short* Vth = Kl  + PL;
    unsigned short* Vtl = Vth + PL;
    unsigned short* xh  = Vtl + PL;
    unsigned short* xl  = xh  + PL;
    // aliases (stream-ordered reuse):
    unsigned short* wqh = (unsigned short*)d_out;          // dead before gemm2 writes
    unsigned short* wql = wqh + (size_t)DQKV * D_MODEL;
    unsigned short* aoh = xh;                              // x dead after gemm1
    unsigned short* aol = xl;
    unsigned short* woh = Qh;                              // Q planes dead after attn
    unsigned short* wol = Qh + (size_t)D_MODEL * D_MODEL;

    dim3 blk(256);
    split_f32_bf16<<<1024, blk, 0, stream>>>(x, xh, xl, M * D_MODEL / 4);
    split_f32_bf16<<<1024, blk, 0, stream>>>(w_qkv, wqh, wql, DQKV * D_MODEL / 4);

    gemm_mfma_qkv<<<dim3(DQKV / 128, M / 128), blk, 0, stream>>>(
        xh, xl, wqh, wql, b_qkv, Qh, Ql, Kh, Kl, Vth, Vtl, M, DQKV, D_MODEL);

    attn_mfma_kernel<<<dim3(512), dim3(512), 0, stream>>>(Qh, Ql, Kh, Kl, Vth, Vtl, aoh, aol);

    split_f32_bf16<<<512, blk, 0, stream>>>(w_out, woh, wol, D_MODEL * D_MODEL / 4);

    gemm_mfma_split<<<dim3(D_MODEL / 128, M / 128), blk, 0, stream>>>(
        aoh, aol, woh, wol, b_out, out, M, D_MODEL, D_MODEL);
}

// Round 6
// 145.187 us; speedup vs baseline: 2.0948x; 2.0218x over previous
//
#include <hip/hip_runtime.h>
#include <hip/hip_bf16.h>

#define D_MODEL 1024
#define S_LEN   2048
#define NBATCH  2
#define NHEADS  16
#define HDIM    64
#define DQKV    3072   // 3 * D_MODEL

typedef short bf16x8 __attribute__((ext_vector_type(8)));
typedef float f32x4  __attribute__((ext_vector_type(4)));
typedef float f32x16 __attribute__((ext_vector_type(16)));
typedef unsigned int u32;

// ---------------------------------------------------------------------------
__device__ __forceinline__ unsigned short bf16_rne(float f) {
    unsigned u = __float_as_uint(f);
    return (unsigned short)((u + 0x7FFFu + ((u >> 16) & 1u)) >> 16);
}

// f32 -> bf16 cast (single plane)
__global__ __launch_bounds__(256) void cast_f32_bf16(
    const float* __restrict__ in, unsigned short* __restrict__ out, int n4)
{
    int i = blockIdx.x * blockDim.x + threadIdx.x;
    const int stride = gridDim.x * blockDim.x;
    for (; i < n4; i += stride) {
        float4 v = ((const float4*)in)[i];
        ((ushort4*)out)[i] = make_ushort4(bf16_rne(v.x), bf16_rne(v.y),
                                          bf16_rne(v.z), bf16_rne(v.w));
    }
}

__device__ __forceinline__ void gld_lds16(const unsigned short* g, unsigned short* l) {
    __builtin_amdgcn_global_load_lds(
        (const __attribute__((address_space(1))) unsigned int*)g,
        (__attribute__((address_space(3))) unsigned int*)l, 16, 0, 0);
}

// Swizzled LDS fragment read: tile rows of 64 ushort (128B), byte ^= (row&7)<<4
__device__ __forceinline__ bf16x8 lds_frag(const unsigned short* base, int row, int e8) {
    int byte = (row << 7) + (e8 << 4);
    byte ^= (row & 7) << 4;
    return *(const bf16x8*)((const char*)base + byte);
}

// ---------------------------------------------------------------------------
// bf16 GEMM core (m97 structure): C_tile = A[M][K] * B[N][K]^T.
// 128x128 tile, BK=32, 4 waves, 16 MFMA (16x16x32) per K-step.
// Waves 0,1 stage A halves; waves 2,3 stage B halves (2 x 8KB LDS planes).
// ---------------------------------------------------------------------------
#define GEMM_CORE(A_, B_, K_)                                                  \
    __shared__ unsigned short sA[128 * 32];                                    \
    __shared__ unsigned short sB[128 * 32];                                    \
    const int tid  = threadIdx.x;                                              \
    const int lane = tid & 63;                                                 \
    const int wid  = tid >> 6;                                                 \
    const int bm = blockIdx.y * 128, bn = blockIdx.x * 128;                    \
    const int wr = (wid >> 1) * 64, wc = (wid & 1) * 64;                       \
    const int half = wid & 1;                                                  \
    const unsigned short* gsrc = (wid < 2) ? A_ : B_;                          \
    unsigned short* ldst = ((wid < 2) ? sA : sB) + half * 2048;                \
    const int brow = ((wid < 2) ? bm : bn) + half * 64;                        \
    const size_t rowbase = (size_t)(brow + (lane >> 2)) * K_ + (lane & 3) * 8; \
    f32x4 acc[4][4];                                                           \
    _Pragma("unroll")                                                          \
    for (int m = 0; m < 4; ++m)                                                \
        _Pragma("unroll")                                                      \
        for (int n = 0; n < 4; ++n)                                            \
            acc[m][n] = f32x4{0.f, 0.f, 0.f, 0.f};                             \
    const int frA = (wr + (lane & 15)) * 32 + (lane >> 4) * 8;                 \
    const int frB = (wc + (lane & 15)) * 32 + (lane >> 4) * 8;                 \
    for (int k0 = 0; k0 < K_; k0 += 32) {                                      \
        __syncthreads();                                                       \
        const unsigned short* g = gsrc + rowbase + k0;                         \
        _Pragma("unroll")                                                      \
        for (int c = 0; c < 4; ++c)                                            \
            gld_lds16(g + (size_t)c * 16 * K_, ldst + c * 512);                \
        __syncthreads();                                                       \
        bf16x8 a[4], b[4];                                                     \
        _Pragma("unroll")                                                      \
        for (int m = 0; m < 4; ++m) a[m] = *(const bf16x8*)&sA[frA + m * 512]; \
        _Pragma("unroll")                                                      \
        for (int n = 0; n < 4; ++n) b[n] = *(const bf16x8*)&sB[frB + n * 512]; \
        _Pragma("unroll")                                                      \
        for (int m = 0; m < 4; ++m)                                            \
            _Pragma("unroll")                                                  \
            for (int n = 0; n < 4; ++n)                                        \
                acc[m][n] = __builtin_amdgcn_mfma_f32_16x16x32_bf16(           \
                    a[m], b[n], acc[m][n], 0, 0, 0);                           \
    }

// out-projection: f32 C with bias
__global__ __launch_bounds__(256) void gemm_mfma_out(
    const unsigned short* __restrict__ A, const unsigned short* __restrict__ B,
    const float* __restrict__ bias, float* __restrict__ C, int M, int N, int K)
{
    GEMM_CORE(A, B, K)
    #pragma unroll
    for (int n = 0; n < 4; ++n) {
        const int col = bn + wc + n * 16 + (lane & 15);
        const float bv = bias[col];
        #pragma unroll
        for (int m = 0; m < 4; ++m) {
            const int row0 = bm + wr + m * 16 + (lane >> 4) * 4;
            #pragma unroll
            for (int j = 0; j < 4; ++j)
                C[(size_t)(row0 + j) * N + col] = acc[m][n][j] + bv;
        }
    }
}

// QKV projection: scatter epilogue into single bf16 planes
//   Q [b,h,s,d] pre-scaled by log2(e)/8, K [b,h,s,d], Vt [b,h,d,s]
__global__ __launch_bounds__(256) void gemm_mfma_qkv(
    const unsigned short* __restrict__ A, const unsigned short* __restrict__ B,
    const float* __restrict__ bias,
    unsigned short* __restrict__ Qs, unsigned short* __restrict__ Ks,
    unsigned short* __restrict__ Vt, int M, int N, int K)
{
    GEMM_CORE(A, B, K)
    #pragma unroll
    for (int n = 0; n < 4; ++n) {
        const int col = bn + wc + n * 16 + (lane & 15);
        const unsigned head = (unsigned)col / 192u;
        const int c = col - (int)head * 192;
        const int cls = c >> 6;                    // 0=q 1=k 2=v (uniform per n)
        const float bv = bias[col];
        #pragma unroll
        for (int m = 0; m < 4; ++m) {
            const int row0 = bm + wr + m * 16 + (lane >> 4) * 4;
            #pragma unroll
            for (int j = 0; j < 4; ++j) {
                const int row = row0 + j;
                const int bb = row >> 11, ss = row & 2047;
                float val = acc[m][n][j] + bv;
                if (cls == 0) val *= 0.18033688011110918f;  // (1/8)*log2(e)
                const unsigned short v = bf16_rne(val);
                if (cls == 2) {
                    Vt[((size_t)(bb * NHEADS + head) * HDIM + (c - 128)) * S_LEN + ss] = v;
                } else {
                    const size_t idx = ((size_t)(bb * NHEADS + head) * S_LEN + ss) * HDIM + (c & 63);
                    if (cls == 0) Qs[idx] = v; else Ks[idx] = v;
                }
            }
        }
    }
}

// ---------------------------------------------------------------------------
// Full-bf16 MFMA flash attention, kv-split, double-buffered.
// Grid: 512 blocks x 8 waves. par=wid>>2 handles even/odd 64-kv tiles;
// wq=wid&3 owns 32 q-columns; parity pair merges (m,l,O) at the end.
// LDS: [2 buf][2 par][K|V][64x64 bf16] = 64KB. Swapped QK^T; exp2-domain
// softmax (Q pre-scaled by log2e/8); defer-max; single-bf16 P via cvt_pk.
// ---------------------------------------------------------------------------
__global__ __launch_bounds__(512) void attn_mfma_kernel(
    const unsigned short* __restrict__ Qs, const unsigned short* __restrict__ Ks,
    const unsigned short* __restrict__ Vt, unsigned short* __restrict__ ob)
{
    __shared__ unsigned short smem[2][2][2][4096];   // [buf][par][cls][64*64]

    const int tid  = threadIdx.x;
    const int lane = tid & 63;
    const int wid  = tid >> 6;         // 0..7
    const int wq   = wid & 3;          // q sub-tile (32 cols)
    const int par  = wid >> 2;         // kv parity
    const int h    = lane >> 5;        // k-octet half
    const int qcol = lane & 31;

    // XCD-chunked remap: 512 blocks, XCD = bid%8 gets a contiguous 64-chunk
    const int bid = blockIdx.x;
    const int lb  = (bid & 7) * 64 + (bid >> 3);
    const int qt  = lb & 15;
    const int bh  = lb >> 4;
    const int q0  = qt * 128 + wq * 32;

    // ---- Q fragments in registers (pre-scaled at GEMM1) ----
    bf16x8 qf[4];
    {
        const unsigned short* qr = Qs + ((size_t)bh * S_LEN + q0 + qcol) * HDIM + h * 8;
        #pragma unroll
        for (int ks = 0; ks < 4; ++ks) qf[ks] = *(const bf16x8*)(qr + ks * 16);
    }

    // ---- staging: wave stages half a plane (4KB = 4 chunks) ----
    const unsigned short* gKV = (wq < 2) ? Ks : Vt;
    const int cls   = wq >> 1;                       // 0=K, 1=V
    const int cbase = (wq & 1) * 4;                  // chunk range
    const int r8    = lane >> 3;                     // row within 8-row chunk
    const int colb  = ((lane & 7) ^ r8) << 3;        // inverse-swizzled col

    float m_run = -1e30f, l_run = 0.0f;
    f32x16 accO[2];
    #pragma unroll
    for (int m = 0; m < 2; ++m)
        #pragma unroll
        for (int r = 0; r < 16; ++r) accO[m][r] = 0.0f;

    #define STAGE(buf, kt)                                                          \
        do {                                                                        \
            unsigned short* pl_ = &smem[buf][par][cls][0];                          \
            if (cls == 0) {                                                         \
                const unsigned short* g_ = gKV + ((size_t)bh * S_LEN + (kt) + r8) * HDIM + colb; \
                _Pragma("unroll")                                                   \
                for (int c_ = 0; c_ < 4; ++c_)                                      \
                    gld_lds16(g_ + (size_t)(cbase + c_) * 8 * HDIM,                 \
                              pl_ + (cbase + c_) * 512);                            \
            } else {                                                                \
                const unsigned short* g_ = gKV + ((size_t)bh * HDIM + r8) * S_LEN + (kt) + colb; \
                _Pragma("unroll")                                                   \
                for (int c_ = 0; c_ < 4; ++c_)                                      \
                    gld_lds16(g_ + (size_t)(cbase + c_) * 8 * S_LEN,                \
                              pl_ + (cbase + c_) * 512);                            \
            }                                                                       \
        } while (0)

    STAGE(0, par * 64);
    __syncthreads();

    int cur = 0;
    for (int it = 0; it < S_LEN / 128; ++it) {       // 16 iterations
        if (it + 1 < S_LEN / 128) STAGE(cur ^ 1, (it + 1) * 128 + par * 64);

        const unsigned short* cK = &smem[cur][par][0][0];
        const unsigned short* cV = &smem[cur][par][1][0];

        // ---- S^T = K . Q^T : accS[mm] is 32kv x 32q, lane owns q=qcol ----
        f32x16 accS[2];
        #pragma unroll
        for (int mm = 0; mm < 2; ++mm)
            #pragma unroll
            for (int r = 0; r < 16; ++r) accS[mm][r] = 0.0f;

        __builtin_amdgcn_s_setprio(1);
        #pragma unroll
        for (int ks = 0; ks < 4; ++ks) {
            const int e8 = ks * 2 + h;
            #pragma unroll
            for (int mm = 0; mm < 2; ++mm) {
                bf16x8 ak = lds_frag(cK, mm * 32 + qcol, e8);
                accS[mm] = __builtin_amdgcn_mfma_f32_32x32x16_bf16(ak, qf[ks], accS[mm], 0, 0, 0);
            }
        }
        __builtin_amdgcn_s_setprio(0);

        // ---- online softmax (exp2 domain), tree reductions, defer-max ----
        float p[32];
        #pragma unroll
        for (int mm = 0; mm < 2; ++mm)
            #pragma unroll
            for (int r = 0; r < 16; ++r) p[mm * 16 + r] = accS[mm][r];

        float t16[16];
        #pragma unroll
        for (int i = 0; i < 16; ++i) t16[i] = fmaxf(p[i], p[i + 16]);
        float t8[8];
        #pragma unroll
        for (int i = 0; i < 8; ++i) t8[i] = fmaxf(t16[i], t16[i + 8]);
        float t4[4];
        #pragma unroll
        for (int i = 0; i < 4; ++i) t4[i] = fmaxf(t8[i], t8[i + 4]);
        float mx = fmaxf(fmaxf(t4[0], t4[1]), fmaxf(t4[2], t4[3]));
        mx = fmaxf(mx, __shfl_xor(mx, 32));

        if (!__all(mx <= m_run + 8.0f)) {
            const float mnew = fmaxf(m_run, mx);
            const float corr = __builtin_amdgcn_exp2f(m_run - mnew);
            m_run = mnew;
            l_run *= corr;
            #pragma unroll
            for (int m = 0; m < 2; ++m)
                #pragma unroll
                for (int r = 0; r < 16; ++r) accO[m][r] *= corr;
        }

        #pragma unroll
        for (int i = 0; i < 32; ++i) p[i] = __builtin_amdgcn_exp2f(p[i] - m_run);
        float s16[16];
        #pragma unroll
        for (int i = 0; i < 16; ++i) s16[i] = p[i] + p[i + 16];
        float s8[8];
        #pragma unroll
        for (int i = 0; i < 8; ++i) s8[i] = s16[i] + s16[i + 8];
        float s4[4];
        #pragma unroll
        for (int i = 0; i < 4; ++i) s4[i] = s8[i] + s8[i + 4];
        float rs = (s4[0] + s4[1]) + (s4[2] + s4[3]);
        rs += __shfl_xor(rs, 32);
        l_run += rs;

        // ---- P^T -> bf16 B-fragments (cvt_pk + shfl_xor(32)) + PV ----
        const bool hib = (h != 0);
        #pragma unroll
        for (int mm = 0; mm < 2; ++mm) {
            u32 wh_[8], sh_[8];
            #pragma unroll
            for (int i = 0; i < 8; ++i) {
                const float pe = p[mm * 16 + 2 * i], po = p[mm * 16 + 2 * i + 1];
                asm("v_cvt_pk_bf16_f32 %0, %1, %2" : "=v"(wh_[i]) : "v"(pe), "v"(po));
            }
            #pragma unroll
            for (int i = 0; i < 8; ++i) sh_[i] = __shfl_xor(wh_[i], 32);
            #pragma unroll
            for (int cc = 0; cc < 2; ++cc) {
                const int b0 = cc * 4;
                union { u32 w[4]; bf16x8 v; } uh;
                uh.w[0] = hib ? sh_[b0 + 2] : wh_[b0 + 0];
                uh.w[1] = hib ? sh_[b0 + 3] : wh_[b0 + 1];
                uh.w[2] = hib ? wh_[b0 + 2] : sh_[b0 + 0];
                uh.w[3] = hib ? wh_[b0 + 3] : sh_[b0 + 1];
                const int e8 = (mm * 2 + cc) * 2 + h;   // kv octet
                #pragma unroll
                for (int mdc = 0; mdc < 2; ++mdc) {
                    bf16x8 vf = lds_frag(cV, mdc * 32 + qcol, e8);
                    accO[mdc] = __builtin_amdgcn_mfma_f32_32x32x16_bf16(vf, uh.v, accO[mdc], 0, 0, 0);
                }
            }
        }

        __syncthreads();   // cur reads done + next stage (vmcnt) drained
        cur ^= 1;
    }
    #undef STAGE

    // ---- merge parity pair states via LDS, then epilogue (par 0 writes) ----
    float* mbuf = (float*)&smem[0][0][0][0];
    if (par == 1) {
        float* dst = mbuf + ((size_t)(wq * 64 + lane)) * 35;  // stride 35: conflict-free
        #pragma unroll
        for (int mdc = 0; mdc < 2; ++mdc)
            #pragma unroll
            for (int r = 0; r < 16; ++r) dst[mdc * 16 + r] = accO[mdc][r];
        dst[32] = m_run;
        dst[33] = l_run;
    }
    __syncthreads();
    if (par == 0) {
        const float* src = mbuf + ((size_t)(wq * 64 + lane)) * 35;
        const float m2 = src[32], l2 = src[33];
        const float mt = fmaxf(m_run, m2);
        const float w1 = __builtin_amdgcn_exp2f(m_run - mt);
        const float w2 = __builtin_amdgcn_exp2f(m2 - mt);
        const float inv = 1.0f / (l_run * w1 + l2 * w2);

        const int bb = bh >> 4, hh = bh & 15;
        const int ss = q0 + qcol;
        unsigned short* po = ob + ((size_t)(bb * S_LEN + ss)) * D_MODEL + hh * HDIM;
        #pragma unroll
        for (int mdc = 0; mdc < 2; ++mdc)
            #pragma unroll
            for (int r = 0; r < 16; r += 2) {
                const int d = mdc * 32 + (r & 3) + 8 * (r >> 2) + 4 * h;
                const float v0 = (accO[mdc][r]     * w1 + src[mdc * 16 + r]     * w2) * inv;
                const float v1 = (accO[mdc][r + 1] * w1 + src[mdc * 16 + r + 1] * w2) * inv;
                *(u32*)(po + d) = ((u32)bf16_rne(v1) << 16) | bf16_rne(v0);
            }
    }
}

// ---------------------------------------------------------------------------
extern "C" void kernel_launch(void* const* d_in, const int* in_sizes, int n_in,
                              void* d_out, int out_size, void* d_ws, size_t ws_size,
                              hipStream_t stream)
{
    const float* x     = (const float*)d_in[0];
    const float* w_qkv = (const float*)d_in[1];
    const float* b_qkv = (const float*)d_in[2];
    const float* w_out = (const float*)d_in[3];
    const float* b_out = (const float*)d_in[4];
    float* out = (float*)d_out;

    const int M = NBATCH * S_LEN;  // 4096
    const size_t PL = (size_t)32 * S_LEN * HDIM;   // 4,194,304 elems

    // ws layout (50.3 MB of >= 67 MB):
    unsigned short* xb  = (unsigned short*)d_ws;           // 4M elems
    unsigned short* wqb = xb  + PL;                        // 3M
    unsigned short* wob = wqb + (size_t)DQKV * D_MODEL;    // 1M
    unsigned short* Qs  = wob + (size_t)D_MODEL * D_MODEL; // 4M
    unsigned short* Ks  = Qs  + PL;
    unsigned short* Vt  = Ks  + PL;
    unsigned short* aob = Vt  + PL;                        // 4M

    dim3 blk(256);
    cast_f32_bf16<<<1024, blk, 0, stream>>>(x, xb, (int)(PL / 4));
    cast_f32_bf16<<<1024, blk, 0, stream>>>(w_qkv, wqb, DQKV * D_MODEL / 4);
    cast_f32_bf16<<<512,  blk, 0, stream>>>(w_out, wob, D_MODEL * D_MODEL / 4);

    gemm_mfma_qkv<<<dim3(DQKV / 128, M / 128), blk, 0, stream>>>(
        xb, wqb, b_qkv, Qs, Ks, Vt, M, DQKV, D_MODEL);

    attn_mfma_kernel<<<dim3(512), dim3(512), 0, stream>>>(Qs, Ks, Vt, aob);

    gemm_mfma_out<<<dim3(D_MODEL / 128, M / 128), blk, 0, stream>>>(
        aob, wob, b_out, out, M, D_MODEL, D_MODEL);
}